// Round 8
// baseline (168.799 us; speedup 1.0000x reference)
//
#include <hip/hip_runtime.h>

#define KLEN 2048
#define SCH 16          // trellis steps per thread (amortize scan cost)
#define TPR 128         // threads per row (2 waves)
#define NEGV (-1e4f)

// Packed fp32 pair: gfx950 has v_pk_add_f32 (VOP3P) -> 2 adds/instr.
// No packed fp32 max exists, so maxes stay scalar (v_max3 + v_max).
typedef float v2f __attribute__((ext_vector_type(2)));

// Matrix layout: M[i*2+jp] = (M[i][2*jp], M[i][2*jp+1])  (row-major column-pairs)

struct SM {
  float y1[KLEN];             // systematic, natural order
  float y1i[KLEN];            // systematic, interleaved
  float Lint[KLEN];           // La for decoder 1 (natural)
  float A[KLEN];              // La for decoder 2 (interleaved); bits staging
  unsigned short perm[KLEN];
  unsigned short invp[KLEN];
  v2f fT[2][8];               // per-wave totals (fwd total == bwd total)
  v2f rT[2][4][8];            // per-wave per-row totals (from bwd in-row scan)
  unsigned int eT[2][2];      // encoder wave totals
};

__device__ __forceinline__ float max4(float a, float b, float c, float d) {
  return fmaxf(fmaxf(fmaxf(a, b), c), d);   // v_max3 + v_max
}

__device__ __forceinline__ v2f mk2(float a, float b) {
  v2f r; r.x = a; r.y = b; return r;
}

__device__ __forceinline__ v2f vmax2(v2f a, v2f b) {
  v2f r; r.x = fmaxf(a.x, b.x); r.y = fmaxf(a.y, b.y); return r;
}

// DPP shift with old = inline 0, bound_ctrl=1: no register tie, invalid lanes -> 0
// (those lanes are exec-predicated off in every consumer).
template <int CTRL>
__device__ __forceinline__ float dppf(float src) {
  return __int_as_float(__builtin_amdgcn_update_dpp(
      0, __float_as_int(src), CTRL, 0xF, 0xF, true));
}

template <int CTRL>
__device__ __forceinline__ void shiftM(const v2f (&X)[8], v2f (&T)[8]) {
#pragma unroll
  for (int e = 0; e < 8; ++e) {
    v2f t;
    t.x = dppf<CTRL>(X[e].x);
    t.y = dppf<CTRL>(X[e].y);
    T[e] = t;
  }
}

__device__ __forceinline__ void cp8(v2f (&D)[8], const v2f (&S)[8]) {
#pragma unroll
  for (int e = 0; e < 8; ++e) D[e] = S[e];
}

// X = X (later) (x) Y (earlier), max-plus, IN PLACE in X.
// Safe: X row i is cached in k0..k3 before X row i is overwritten.
__device__ __forceinline__ void combF(v2f (&X)[8], const v2f (&Y)[8]) {
#pragma unroll
  for (int i = 0; i < 4; ++i) {
    const float k0 = X[i * 2].x, k1 = X[i * 2].y;
    const float k2 = X[i * 2 + 1].x, k3 = X[i * 2 + 1].y;
#pragma unroll
    for (int jp = 0; jp < 2; ++jp) {
      v2f t0 = k0 + Y[0 + jp];      // v_pk_add_f32 (splat)
      v2f t1 = k1 + Y[2 + jp];
      v2f t2 = k2 + Y[4 + jp];
      v2f t3 = k3 + Y[6 + jp];
      v2f z;
      z.x = max4(t0.x, t1.x, t2.x, t3.x);
      z.y = max4(t0.y, t1.y, t2.y, t3.y);
      X[i * 2 + jp] = z;
    }
  }
}

// Y = X (later) (x) Y (earlier), max-plus, IN PLACE in Y.
// Safe: for each column-pair jp, Y[*][jp] is cached before being overwritten.
__device__ __forceinline__ void combB(const v2f (&X)[8], v2f (&Y)[8]) {
#pragma unroll
  for (int jp = 0; jp < 2; ++jp) {
    v2f y0 = Y[0 + jp], y1 = Y[2 + jp], y2 = Y[4 + jp], y3 = Y[6 + jp];
#pragma unroll
    for (int i = 0; i < 4; ++i) {
      v2f t0 = X[i * 2].x + y0;
      v2f t1 = X[i * 2].y + y1;
      v2f t2 = X[i * 2 + 1].x + y2;
      v2f t3 = X[i * 2 + 1].y + y3;
      v2f z;
      z.x = max4(t0.x, t1.x, t2.x, t3.x);
      z.y = max4(t0.y, t1.y, t2.y, t3.y);
      Y[i * 2 + jp] = z;
    }
  }
}

// u' = u (x) T  (row-vector pulled backward through earlier matrix T)
__device__ __forceinline__ void rowmat(float (&u)[4], const v2f* T) {
  v2f t0 = u[0] + T[0], t1 = u[1] + T[2], t2 = u[2] + T[4], t3 = u[3] + T[6];
  v2f s0 = u[0] + T[1], s1 = u[1] + T[3], s2 = u[2] + T[5], s3 = u[3] + T[7];
  float c0 = max4(t0.x, t1.x, t2.x, t3.x);
  float c1 = max4(t0.y, t1.y, t2.y, t3.y);
  float c2 = max4(s0.x, s1.x, s2.x, s3.x);
  float c3 = max4(s0.y, s1.y, s2.y, s3.y);
  u[0] = c0; u[1] = c1; u[2] = c2; u[3] = c3;
}

// chunk matrix over SCH steps from butterfly terms x=p+q, y=p-q.
// Steps 0+1 fused (pure adds). NO normalization.
__device__ __forceinline__ void buildM(const float (&x)[SCH], const float (&y)[SCH],
                                       v2f (&M)[8]) {
  const float x0 = x[0], y0 = y[0], x1 = x[1], y1 = y[1];
  M[0] = mk2(-x0 - x1,  x0 - x1);   // row0, j={0,1}
  M[1] = mk2( y0 + x1, -y0 + x1);   // row0, j={2,3}
  M[2] = mk2( x0 + y1, -x0 + y1);   // row1
  M[3] = mk2(-y0 - y1,  y0 - y1);
  M[4] = mk2(-x0 + x1,  x0 + x1);   // row2
  M[5] = mk2( y0 - x1, -y0 - x1);
  M[6] = mk2( x0 - y1, -x0 - y1);   // row3
  M[7] = mk2(-y0 + y1,  y0 + y1);
#pragma unroll
  for (int k = 2; k < SCH; ++k) {
    const float p = x[k], q = y[k];
#pragma unroll
    for (int jp = 0; jp < 2; ++jp) {
      v2f r0 = M[0 + jp], r1 = M[2 + jp], r2 = M[4 + jp], r3 = M[6 + jp];
      v2f r0m = r0 - p, r1p = r1 + p, r0p = r0 + p, r1m = r1 - p;
      v2f r2p = r2 + q, r3m = r3 - q, r2m = r2 - q, r3p = r3 + q;
      M[0 + jp] = vmax2(r0m, r1p);
      M[4 + jp] = vmax2(r0p, r1m);
      M[2 + jp] = vmax2(r2p, r3m);
      M[6 + jp] = vmax2(r2m, r3p);
    }
  }
}

// one BCJR pass: 2 waves x 64 lanes x SCH steps; matrix scan + vector tails.
__device__ __forceinline__ void bcjr_pass(
    const float* ys, const float* La, float* dst, const int (&wi)[SCH],
    int finalLLR, const float (&q)[SCH], v2f (&fT)[2][8], v2f (&rT)[2][4][8],
    int base, int lane, int w) {
  float x[SCH], y[SCH];
  {
    const float4* y4 = (const float4*)(ys + base);
    const float4* l4 = (const float4*)(La + base);
#pragma unroll
    for (int k = 0; k < SCH / 4; ++k) {
      float4 yv = y4[k], lv = l4[k];
      float p0 = yv.x + 0.5f * lv.x, p1 = yv.y + 0.5f * lv.y;
      float p2 = yv.z + 0.5f * lv.z, p3 = yv.w + 0.5f * lv.w;
      x[4 * k + 0] = p0 + q[4 * k + 0]; y[4 * k + 0] = p0 - q[4 * k + 0];
      x[4 * k + 1] = p1 + q[4 * k + 1]; y[4 * k + 1] = p1 - q[4 * k + 1];
      x[4 * k + 2] = p2 + q[4 * k + 2]; y[4 * k + 2] = p2 - q[4 * k + 2];
      x[4 * k + 3] = p3 + q[4 * k + 3]; y[4 * k + 3] = p3 - q[4 * k + 3];
    }
  }

  v2f P[8];
  buildM(x, y, P);
  v2f Q[8];
  cp8(Q, P);

  const int rl = lane & 15;
  const int row = lane >> 4;

  // ---- fwd prefix scan (6 levels) and bwd in-row suffix scan (4 levels),
  // predicated combs, chains interleaved (verified round-7 structure). ----
  {
    v2f Tf[8], Tb[8];
    shiftM<0x111>(P, Tf);  shiftM<0x101>(Q, Tb);
    if (rl >= 1)  combF(P, Tf);
    if (rl <= 14) combB(Tb, Q);
    shiftM<0x112>(P, Tf);  shiftM<0x102>(Q, Tb);
    if (rl >= 2)  combF(P, Tf);
    if (rl <= 13) combB(Tb, Q);
    shiftM<0x114>(P, Tf);  shiftM<0x104>(Q, Tb);
    if (rl >= 4)  combF(P, Tf);
    if (rl <= 11) combB(Tb, Q);
    shiftM<0x118>(P, Tf);  shiftM<0x108>(Q, Tb);
    if (rl >= 8)  combF(P, Tf);
    if (rl <= 7)  combB(Tb, Q);
    if (rl == 0) cp8(rT[w][row], Q);            // Q final; overlaps bcast levels
    shiftM<0x142>(P, Tf); if (row & 1)  combF(P, Tf);   // bcast15
    shiftM<0x143>(P, Tf); if (row >= 2) combF(P, Tf);   // bcast31
    if (lane == 63) cp8(fT[w], P);
  }
  __syncthreads();

  // ---- forward vector chain: f = col0 of earlier wave's total (2 waves) ----
  float f[4];
  if (w == 0) { f[0] = 0.f; f[1] = NEGV; f[2] = NEGV; f[3] = NEGV; }
  else {
    f[0] = fT[0][0].x; f[1] = fT[0][2].x; f[2] = fT[0][4].x; f[3] = fT[0][6].x;
  }
  // ---- backward vector chain: u = colmax over later wave's total ----
  float u[4];
  if (w == 1) { u[0] = u[1] = u[2] = u[3] = 0.f; }
  else {
    const v2f* T1 = fT[1];
    u[0] = max4(T1[0].x, T1[2].x, T1[4].x, T1[6].x);
    u[1] = max4(T1[0].y, T1[2].y, T1[4].y, T1[6].y);
    u[2] = max4(T1[1].x, T1[3].x, T1[5].x, T1[7].x);
    u[3] = max4(T1[1].y, T1[3].y, T1[5].y, T1[7].y);
  }
  // ---- extend u through later rows' totals within this wave (LDS row totals) ----
#pragma unroll
  for (int jj = 3; jj >= 1; --jj) {
    if (row < jj) rowmat(u, rT[w][jj]);
  }

  // ---- alpha at chunk start: v = P (x) f (inclusive), then shift by one lane ----
  float a[4];
  {
    v2f F0 = mk2(f[0], f[1]), F1 = mk2(f[2], f[3]);
    v2f t0 = P[0] + F0, t0b = P[1] + F1;
    v2f t1 = P[2] + F0, t1b = P[3] + F1;
    v2f t2 = P[4] + F0, t2b = P[5] + F1;
    v2f t3 = P[6] + F0, t3b = P[7] + F1;
    float v0 = max4(t0.x, t0.y, t0b.x, t0b.y);
    float v1 = max4(t1.x, t1.y, t1b.x, t1b.y);
    float v2 = max4(t2.x, t2.y, t2b.x, t2b.y);
    float v3 = max4(t3.x, t3.y, t3b.x, t3b.y);
    float a0 = __shfl(v0, lane - 1), a1 = __shfl(v1, lane - 1);
    float a2 = __shfl(v2, lane - 1), a3 = __shfl(v3, lane - 1);
    if (lane == 0) { a0 = f[0]; a1 = f[1]; a2 = f[2]; a3 = f[3]; }
    a[0] = 0.f; a[1] = a1 - a0; a[2] = a2 - a0; a[3] = a3 - a0;
  }

  // ---- beta at chunk end: z = u (x) Q (inclusive suffix colmax), shift by one ----
  float b[4];
  {
    v2f t0 = u[0] + Q[0], t1 = u[1] + Q[2], t2 = u[2] + Q[4], t3 = u[3] + Q[6];
    v2f s0 = u[0] + Q[1], s1 = u[1] + Q[3], s2 = u[2] + Q[5], s3 = u[3] + Q[7];
    float z0 = max4(t0.x, t1.x, t2.x, t3.x);
    float z1 = max4(t0.y, t1.y, t2.y, t3.y);
    float z2 = max4(s0.x, s1.x, s2.x, s3.x);
    float z3 = max4(s0.y, s1.y, s2.y, s3.y);
    float b0 = __shfl(z0, lane + 1), b1 = __shfl(z1, lane + 1);
    float b2 = __shfl(z2, lane + 1), b3 = __shfl(z3, lane + 1);
    if (lane == 63) { b0 = u[0]; b1 = u[1]; b2 = u[2]; b3 = u[3]; }
    b[0] = 0.f; b[1] = b1 - b0; b[2] = b2 - b0; b[3] = b3 - b0;
  }

  // ---- local beta walk ----
  float bet[SCH][4];
  bet[SCH - 1][0] = b[0]; bet[SCH - 1][1] = b[1];
  bet[SCH - 1][2] = b[2]; bet[SCH - 1][3] = b[3];
#pragma unroll
  for (int k = SCH - 1; k >= 1; --k) {
    float ppq = x[k], pmq = y[k];
    float B0 = bet[k][0], B1 = bet[k][1], B2 = bet[k][2], B3 = bet[k][3];
    bet[k - 1][0] = fmaxf(B0 - ppq, B2 + ppq);
    bet[k - 1][1] = fmaxf(B2 - ppq, B0 + ppq);
    bet[k - 1][2] = fmaxf(B3 - pmq, B1 + pmq);
    bet[k - 1][3] = fmaxf(B1 - pmq, B3 + pmq);
  }

  // ---- alpha walk + LLR + scattered write (shared butterfly sums) ----
#pragma unroll
  for (int k = 0; k < SCH; ++k) {
    float ppq = x[k], pmq = y[k];
    float s0m = a[0] - ppq, s1p = a[1] + ppq, s0p = a[0] + ppq, s1m = a[1] - ppq;
    float s2p = a[2] + pmq, s3m = a[3] - pmq, s2m = a[2] - pmq, s3p = a[3] + pmq;
    float B0 = bet[k][0], B1 = bet[k][1], B2 = bet[k][2], B3 = bet[k][3];
    float m1 = max4(s0p + B2, s1p + B0, s2p + B1, s3p + B3);
    float m0 = max4(s0m + B0, s1m + B2, s2m + B3, s3m + B1);
    float llr = m1 - m0;
    // 2*p[k] == x[k] + y[k]
    float val = finalLLR ? llr : (llr - ppq - pmq);
    dst[wi[k]] = val;
    a[0] = fmaxf(s0m, s1p);
    a[2] = fmaxf(s0p, s1m);
    a[1] = fmaxf(s2p, s3m);
    a[3] = fmaxf(s2m, s3p);
  }
}

__device__ __forceinline__ unsigned fsm_compose(unsigned f, unsigned g) {
  unsigned nm = 0;
#pragma unroll
  for (int s = 0; s < 4; ++s) {
    unsigned gs = (g >> (8 * s)) & 3u;
    nm |= ((f >> (8 * gs)) & 0xFFu) << (8 * s);
  }
  return nm;
}

__global__ __launch_bounds__(TPR, 1) void turbo_kernel(
    const int* __restrict__ xg, const float* __restrict__ n1g,
    const float* __restrict__ n2g, const float* __restrict__ n3g,
    const int* __restrict__ pg, float* __restrict__ outg) {
  __shared__ SM sm;
  const int tid = threadIdx.x;
  const int lane = tid & 63, w = tid >> 6;
  const int base = tid * SCH;
  const size_t rb = (size_t)blockIdx.x * KLEN;

  // ---- load inputs ----
  int* Ai = (int*)sm.A;
  for (int i = tid; i < KLEN; i += TPR) {
    sm.perm[i] = (unsigned short)pg[i];
    int xv = xg[rb + i];
    Ai[i] = xv;
    sm.y1[i] = (2.f * xv - 1.f) + n1g[rb + i];
    sm.Lint[i] = 0.f;
  }
  float q2[SCH], q3[SCH];
  {
    size_t g0 = rb + (size_t)base;
#pragma unroll
    for (int k = 0; k < SCH; ++k) { q2[k] = n2g[g0 + k]; q3[k] = n3g[g0 + k]; }
  }
  __syncthreads();

  // ---- one-time: invp, interleaved systematic ----
  for (int i = tid; i < KLEN; i += TPR) {
    sm.invp[sm.perm[i]] = (unsigned short)i;
    sm.y1i[i] = sm.y1[sm.perm[i]];
  }

  // ---- RSC encode via FSM hierarchical scan ----
  unsigned ub1 = 0, ub2 = 0;
#pragma unroll
  for (int k = 0; k < SCH; ++k) {
    int t = base + k;
    ub1 |= (unsigned)(Ai[t] & 1) << k;
    ub2 |= (unsigned)(Ai[sm.perm[t]] & 1) << k;
  }
  unsigned m1 = 0x03020100u, m2 = 0x03020100u;
#pragma unroll
  for (int k = 0; k < SCH; ++k) {
    unsigned st1 = ((ub1 >> k) & 1) ? 0x03010002u : 0x01030200u;
    unsigned st2 = ((ub2 >> k) & 1) ? 0x03010002u : 0x01030200u;
    m1 = fsm_compose(st1, m1);
    m2 = fsm_compose(st2, m2);
  }
#pragma unroll
  for (int i = 0; i < 6; ++i) {
    const int d = 1 << i;
    unsigned t1 = __shfl_up(m1, d), t2 = __shfl_up(m2, d);
    if (lane >= d) { m1 = fsm_compose(m1, t1); m2 = fsm_compose(m2, t2); }
  }
  if (lane == 63) { sm.eT[w][0] = m1; sm.eT[w][1] = m2; }
  __syncthreads();
  {
    unsigned W1 = 0x03020100u, W2 = 0x03020100u;
    if (w >= 1) { W1 = sm.eT[0][0]; W2 = sm.eT[0][1]; }
    unsigned f1 = fsm_compose(m1, W1), f2 = fsm_compose(m2, W2);
    unsigned pf1 = __shfl_up(f1, 1), pf2 = __shfl_up(f2, 1);
    int s1 = (tid == 0) ? 0 : (lane == 0 ? (int)(W1 & 3u) : (int)(pf1 & 3u));
    int s2 = (tid == 0) ? 0 : (lane == 0 ? (int)(W2 & 3u) : (int)(pf2 & 3u));
#pragma unroll
    for (int k = 0; k < SCH; ++k) {
      { int u = (ub1 >> k) & 1, a = u ^ (s1 >> 1) ^ (s1 & 1), par = a ^ (s1 & 1);
        q2[k] += 2.f * par - 1.f; s1 = (a << 1) | (s1 >> 1); }
      { int u = (ub2 >> k) & 1, a = u ^ (s2 >> 1) ^ (s2 & 1), par = a ^ (s2 & 1);
        q3[k] += 2.f * par - 1.f; s2 = (a << 1) | (s2 >> 1); }
    }
  }
  __syncthreads();  // bits consumed; A becomes interleaved-La buffer

  // ---- cache scatter indices in registers (constant across iterations) ----
  int wi1[SCH], wi2[SCH];
#pragma unroll
  for (int k = 0; k < SCH; ++k) {
    wi1[k] = (int)sm.invp[base + k];
    wi2[k] = (int)sm.perm[base + k];
  }

  // ---- 6 turbo iterations ----
#pragma unroll 1
  for (int it = 0; it < 6; ++it) {
    bcjr_pass(sm.y1, sm.Lint, sm.A, wi1, 0, q2, sm.fT, sm.rT, base, lane, w);
    __syncthreads();
    const int fin = (it == 5);
    bcjr_pass(sm.y1i, sm.A, sm.Lint, wi2, fin, q3, sm.fT, sm.rT, base, lane, w);
    __syncthreads();
  }

  // ---- Lint holds deinterleaved L2; coalesced store ----
  for (int i = tid; i < KLEN; i += TPR) outg[rb + i] = sm.Lint[i];
}

extern "C" void kernel_launch(void* const* d_in, const int* in_sizes, int n_in,
                              void* d_out, int out_size, void* d_ws, size_t ws_size,
                              hipStream_t stream) {
  (void)n_in; (void)d_ws; (void)ws_size; (void)out_size;
  const int* x    = (const int*)d_in[0];
  const float* n1 = (const float*)d_in[1];
  const float* n2 = (const float*)d_in[2];
  const float* n3 = (const float*)d_in[3];
  const int* perm = (const int*)d_in[4];
  float* out = (float*)d_out;
  const int K = in_sizes[4];       // 2048
  const int B = in_sizes[0] / K;   // 512 rows, one per block
  turbo_kernel<<<B, TPR, 0, stream>>>(x, n1, n2, n3, perm, out);
}

// Round 10
// 147.119 us; speedup vs baseline: 1.1474x; 1.1474x over previous
//
#include <hip/hip_runtime.h>

#define KLEN 2048
#define SCH 8           // trellis steps per thread
#define TPR 256         // threads per row (4 waves)
#define NEGV (-1e4f)

// Packed fp32 pair: gfx950 has v_pk_add_f32 (VOP3P) -> 2 adds/instr.
// No packed fp32 max exists, so maxes stay scalar (v_max3 + v_max).
typedef float v2f __attribute__((ext_vector_type(2)));

// Matrix layout: M[i*2+jp] = (M[i][2*jp], M[i][2*jp+1])  (row-major column-pairs)

struct SM {
  float y1[KLEN];             // systematic, natural order
  float y1i[KLEN];            // systematic, interleaved
  float Lint[KLEN];           // La for decoder 1 (natural)
  float A[KLEN];              // La for decoder 2 (interleaved); bits staging
  unsigned short perm[KLEN];
  unsigned short invp[KLEN];
  v2f fT[4][8];               // per-wave totals (fwd total == bwd total)
  v2f rT[4][4][8];            // per-wave per-row totals (from bwd in-row scan)
  unsigned int eT[4][2];      // encoder wave totals
};

__device__ __forceinline__ float max4(float a, float b, float c, float d) {
  return fmaxf(fmaxf(fmaxf(a, b), c), d);   // v_max3 + v_max
}

__device__ __forceinline__ v2f mk2(float a, float b) {
  v2f r; r.x = a; r.y = b; return r;
}

__device__ __forceinline__ v2f vmax2(v2f a, v2f b) {
  v2f r; r.x = fmaxf(a.x, b.x); r.y = fmaxf(a.y, b.y); return r;
}

// DPP shift with old = inline 0, bound_ctrl=1: no register tie, invalid lanes -> 0
// (those lanes are exec-predicated off in every consumer).
template <int CTRL>
__device__ __forceinline__ float dppf(float src) {
  return __int_as_float(__builtin_amdgcn_update_dpp(
      0, __float_as_int(src), CTRL, 0xF, 0xF, true));
}

template <int CTRL>
__device__ __forceinline__ void shiftM(const v2f (&X)[8], v2f (&T)[8]) {
#pragma unroll
  for (int e = 0; e < 8; ++e) {
    v2f t;
    t.x = dppf<CTRL>(X[e].x);
    t.y = dppf<CTRL>(X[e].y);
    T[e] = t;
  }
}

__device__ __forceinline__ void cp8(v2f (&D)[8], const v2f (&S)[8]) {
#pragma unroll
  for (int e = 0; e < 8; ++e) D[e] = S[e];
}

// X = X (later) (x) Y (earlier), max-plus, IN PLACE in X.
// Safe: X row i is cached in k0..k3 before X row i is overwritten.
__device__ __forceinline__ void combF(v2f (&X)[8], const v2f (&Y)[8]) {
#pragma unroll
  for (int i = 0; i < 4; ++i) {
    const float k0 = X[i * 2].x, k1 = X[i * 2].y;
    const float k2 = X[i * 2 + 1].x, k3 = X[i * 2 + 1].y;
#pragma unroll
    for (int jp = 0; jp < 2; ++jp) {
      v2f t0 = k0 + Y[0 + jp];      // v_pk_add_f32 (splat)
      v2f t1 = k1 + Y[2 + jp];
      v2f t2 = k2 + Y[4 + jp];
      v2f t3 = k3 + Y[6 + jp];
      v2f z;
      z.x = max4(t0.x, t1.x, t2.x, t3.x);
      z.y = max4(t0.y, t1.y, t2.y, t3.y);
      X[i * 2 + jp] = z;
    }
  }
}

// Y = X (later) (x) Y (earlier), max-plus, IN PLACE in Y.
// Safe: for each column-pair jp, Y[*][jp] is cached before being overwritten.
__device__ __forceinline__ void combB(const v2f (&X)[8], v2f (&Y)[8]) {
#pragma unroll
  for (int jp = 0; jp < 2; ++jp) {
    v2f y0 = Y[0 + jp], y1 = Y[2 + jp], y2 = Y[4 + jp], y3 = Y[6 + jp];
#pragma unroll
    for (int i = 0; i < 4; ++i) {
      v2f t0 = X[i * 2].x + y0;
      v2f t1 = X[i * 2].y + y1;
      v2f t2 = X[i * 2 + 1].x + y2;
      v2f t3 = X[i * 2 + 1].y + y3;
      v2f z;
      z.x = max4(t0.x, t1.x, t2.x, t3.x);
      z.y = max4(t0.y, t1.y, t2.y, t3.y);
      Y[i * 2 + jp] = z;
    }
  }
}

// f' = T (x) f  (column-vector pushed forward through later matrix T)
__device__ __forceinline__ void matcol(const v2f* T, float (&f)[4]) {
  v2f F0 = mk2(f[0], f[1]), F1 = mk2(f[2], f[3]);
  v2f t0 = T[0] + F0, t0b = T[1] + F1;
  v2f t1 = T[2] + F0, t1b = T[3] + F1;
  v2f t2 = T[4] + F0, t2b = T[5] + F1;
  v2f t3 = T[6] + F0, t3b = T[7] + F1;
  f[0] = max4(t0.x, t0.y, t0b.x, t0b.y);
  f[1] = max4(t1.x, t1.y, t1b.x, t1b.y);
  f[2] = max4(t2.x, t2.y, t2b.x, t2b.y);
  f[3] = max4(t3.x, t3.y, t3b.x, t3b.y);
}

// u' = u (x) T  (row-vector pulled backward through earlier matrix T)
__device__ __forceinline__ void rowmat(float (&u)[4], const v2f* T) {
  v2f t0 = u[0] + T[0], t1 = u[1] + T[2], t2 = u[2] + T[4], t3 = u[3] + T[6];
  v2f s0 = u[0] + T[1], s1 = u[1] + T[3], s2 = u[2] + T[5], s3 = u[3] + T[7];
  float c0 = max4(t0.x, t1.x, t2.x, t3.x);
  float c1 = max4(t0.y, t1.y, t2.y, t3.y);
  float c2 = max4(s0.x, s1.x, s2.x, s3.x);
  float c3 = max4(s0.y, s1.y, s2.y, s3.y);
  u[0] = c0; u[1] = c1; u[2] = c2; u[3] = c3;
}

// chunk matrix over SCH steps from butterfly terms x=p+q, y=p-q.
// Steps 0+1 fused (pure adds). NO normalization.
__device__ __forceinline__ void buildM(const float (&x)[SCH], const float (&y)[SCH],
                                       v2f (&M)[8]) {
  const float x0 = x[0], y0 = y[0], x1 = x[1], y1 = y[1];
  M[0] = mk2(-x0 - x1,  x0 - x1);   // row0, j={0,1}
  M[1] = mk2( y0 + x1, -y0 + x1);   // row0, j={2,3}
  M[2] = mk2( x0 + y1, -x0 + y1);   // row1
  M[3] = mk2(-y0 - y1,  y0 - y1);
  M[4] = mk2(-x0 + x1,  x0 + x1);   // row2
  M[5] = mk2( y0 - x1, -y0 - x1);
  M[6] = mk2( x0 - y1, -x0 - y1);   // row3
  M[7] = mk2(-y0 + y1,  y0 + y1);
#pragma unroll
  for (int k = 2; k < SCH; ++k) {
    const float p = x[k], q = y[k];
#pragma unroll
    for (int jp = 0; jp < 2; ++jp) {
      v2f r0 = M[0 + jp], r1 = M[2 + jp], r2 = M[4 + jp], r3 = M[6 + jp];
      v2f r0m = r0 - p, r1p = r1 + p, r0p = r0 + p, r1m = r1 - p;
      v2f r2p = r2 + q, r3m = r3 - q, r2m = r2 - q, r3p = r3 + q;
      M[0 + jp] = vmax2(r0m, r1p);
      M[4 + jp] = vmax2(r0p, r1m);
      M[2 + jp] = vmax2(r2p, r3m);
      M[6 + jp] = vmax2(r2m, r3p);
    }
  }
}

// one BCJR pass: 4 waves x 64 lanes x SCH steps; matrix scan + vector tails.
__device__ __forceinline__ void bcjr_pass(
    const float* ys, const float* La, float* dst, const int (&wi)[SCH],
    int finalLLR, const float (&q)[SCH], v2f (&fT)[4][8], v2f (&rT)[4][4][8],
    int base, int lane, int w) {
  float x[SCH], y[SCH];
  {
    const float4* y4 = (const float4*)(ys + base);
    const float4* l4 = (const float4*)(La + base);
#pragma unroll
    for (int k = 0; k < SCH / 4; ++k) {
      float4 yv = y4[k], lv = l4[k];
      float p0 = yv.x + 0.5f * lv.x, p1 = yv.y + 0.5f * lv.y;
      float p2 = yv.z + 0.5f * lv.z, p3 = yv.w + 0.5f * lv.w;
      x[4 * k + 0] = p0 + q[4 * k + 0]; y[4 * k + 0] = p0 - q[4 * k + 0];
      x[4 * k + 1] = p1 + q[4 * k + 1]; y[4 * k + 1] = p1 - q[4 * k + 1];
      x[4 * k + 2] = p2 + q[4 * k + 2]; y[4 * k + 2] = p2 - q[4 * k + 2];
      x[4 * k + 3] = p3 + q[4 * k + 3]; y[4 * k + 3] = p3 - q[4 * k + 3];
    }
  }

  v2f P[8];
  buildM(x, y, P);
  v2f Q[8];
  cp8(Q, P);

  const int rl = lane & 15;
  const int row = lane >> 4;

  // ---- fwd prefix scan (6 levels) and bwd in-row suffix scan (4 levels),
  // predicated combs, chains interleaved (verified round-7 structure). ----
  {
    v2f Tf[8], Tb[8];
    shiftM<0x111>(P, Tf);  shiftM<0x101>(Q, Tb);
    if (rl >= 1)  combF(P, Tf);
    if (rl <= 14) combB(Tb, Q);
    shiftM<0x112>(P, Tf);  shiftM<0x102>(Q, Tb);
    if (rl >= 2)  combF(P, Tf);
    if (rl <= 13) combB(Tb, Q);
    shiftM<0x114>(P, Tf);  shiftM<0x104>(Q, Tb);
    if (rl >= 4)  combF(P, Tf);
    if (rl <= 11) combB(Tb, Q);
    shiftM<0x118>(P, Tf);  shiftM<0x108>(Q, Tb);
    if (rl >= 8)  combF(P, Tf);
    if (rl <= 7)  combB(Tb, Q);
    if (rl == 0) cp8(rT[w][row], Q);            // Q final; overlaps bcast levels
    shiftM<0x142>(P, Tf); if (row & 1)  combF(P, Tf);   // bcast15
    shiftM<0x143>(P, Tf); if (row >= 2) combF(P, Tf);   // bcast31
    if (lane == 63) cp8(fT[w], P);
  }
  __syncthreads();

  // ---- forward vector chain: f = col0 of product of earlier waves' totals ----
  float f[4];
  if (w == 0) { f[0] = 0.f; f[1] = NEGV; f[2] = NEGV; f[3] = NEGV; }
  else {
    f[0] = fT[0][0].x; f[1] = fT[0][2].x; f[2] = fT[0][4].x; f[3] = fT[0][6].x;
    if (w >= 2) matcol(fT[1], f);
    if (w >= 3) matcol(fT[2], f);
  }
  // ---- backward vector chain: u = colmax over later waves' totals ----
  float u[4];
  if (w == 3) { u[0] = u[1] = u[2] = u[3] = 0.f; }
  else {
    const v2f* T3 = fT[3];
    u[0] = max4(T3[0].x, T3[2].x, T3[4].x, T3[6].x);
    u[1] = max4(T3[0].y, T3[2].y, T3[4].y, T3[6].y);
    u[2] = max4(T3[1].x, T3[3].x, T3[5].x, T3[7].x);
    u[3] = max4(T3[1].y, T3[3].y, T3[5].y, T3[7].y);
    if (w <= 1) rowmat(u, fT[2]);
    if (w == 0) rowmat(u, fT[1]);
  }
  // ---- extend u through later rows' totals within this wave (LDS row totals) ----
#pragma unroll
  for (int jj = 3; jj >= 1; --jj) {
    if (row < jj) rowmat(u, rT[w][jj]);
  }

  // ---- alpha at chunk start: v = P (x) f (inclusive), then shift by one lane ----
  float a[4];
  {
    v2f F0 = mk2(f[0], f[1]), F1 = mk2(f[2], f[3]);
    v2f t0 = P[0] + F0, t0b = P[1] + F1;
    v2f t1 = P[2] + F0, t1b = P[3] + F1;
    v2f t2 = P[4] + F0, t2b = P[5] + F1;
    v2f t3 = P[6] + F0, t3b = P[7] + F1;
    float v0 = max4(t0.x, t0.y, t0b.x, t0b.y);
    float v1 = max4(t1.x, t1.y, t1b.x, t1b.y);
    float v2 = max4(t2.x, t2.y, t2b.x, t2b.y);
    float v3 = max4(t3.x, t3.y, t3b.x, t3b.y);
    float a0 = __shfl(v0, lane - 1), a1 = __shfl(v1, lane - 1);
    float a2 = __shfl(v2, lane - 1), a3 = __shfl(v3, lane - 1);
    if (lane == 0) { a0 = f[0]; a1 = f[1]; a2 = f[2]; a3 = f[3]; }
    a[0] = 0.f; a[1] = a1 - a0; a[2] = a2 - a0; a[3] = a3 - a0;
  }

  // ---- beta at chunk end: z = u (x) Q (inclusive suffix colmax), shift by one ----
  float b[4];
  {
    v2f t0 = u[0] + Q[0], t1 = u[1] + Q[2], t2 = u[2] + Q[4], t3 = u[3] + Q[6];
    v2f s0 = u[0] + Q[1], s1 = u[1] + Q[3], s2 = u[2] + Q[5], s3 = u[3] + Q[7];
    float z0 = max4(t0.x, t1.x, t2.x, t3.x);
    float z1 = max4(t0.y, t1.y, t2.y, t3.y);
    float z2 = max4(s0.x, s1.x, s2.x, s3.x);
    float z3 = max4(s0.y, s1.y, s2.y, s3.y);
    float b0 = __shfl(z0, lane + 1), b1 = __shfl(z1, lane + 1);
    float b2 = __shfl(z2, lane + 1), b3 = __shfl(z3, lane + 1);
    if (lane == 63) { b0 = u[0]; b1 = u[1]; b2 = u[2]; b3 = u[3]; }
    b[0] = 0.f; b[1] = b1 - b0; b[2] = b2 - b0; b[3] = b3 - b0;
  }

  // ---- local beta walk, packed pairs bA=(B0,B2), bB=(B1,B3) ----
  // Verified vs scalar: bA'[.x]=max(B0-p,B2+p), bA'[.y]=max(B1+q,B3-q),
  //                     bB'[.x]=max(B0+p,B2-p), bB'[.y]=max(B1-q,B3+q).
  v2f bA[SCH], bB[SCH];
  bA[SCH - 1] = mk2(b[0], b[2]);
  bB[SCH - 1] = mk2(b[1], b[3]);
#pragma unroll
  for (int k = SCH - 1; k >= 1; --k) {
    const float p = x[k], qq = y[k];
    v2f t1 = bA[k] + mk2(-p,  p);   // (B0-p, B2+p)
    v2f t2 = bA[k] + mk2( p, -p);   // (B0+p, B2-p)
    v2f t3 = bB[k] + mk2( qq, -qq); // (B1+q, B3-q)
    v2f t4 = bB[k] + mk2(-qq,  qq); // (B1-q, B3+q)
    bA[k - 1] = mk2(fmaxf(t1.x, t1.y), fmaxf(t3.x, t3.y));  // (new0,new2)
    bB[k - 1] = mk2(fmaxf(t2.x, t2.y), fmaxf(t4.x, t4.y));  // (new1,new3)
  }

  // ---- alpha walk + LLR + scattered write, packed pairs ----
  // a01=(a0,a1), a23=(a2,a3); identical adds/maxes to the scalar walk.
  v2f a01 = mk2(a[0], a[1]), a23 = mk2(a[2], a[3]);
#pragma unroll
  for (int k = 0; k < SCH; ++k) {
    const float p = x[k], qq = y[k];
    v2f sp01 = a01 + p;             // (s0p, s1p)
    v2f sm01 = a01 - p;             // (s0m, s1m)
    v2f sp23 = a23 + qq;            // (s2p, s3p)
    v2f sm23 = a23 - qq;            // (s2m, s3m)
    v2f BA = bA[k], BB = bB[k];     // (B0,B2), (B1,B3)
    v2f m1a = sp01 + mk2(BA.y, BA.x);   // (s0p+B2, s1p+B0)
    v2f m1b = sp23 + BB;                // (s2p+B1, s3p+B3)
    v2f m0a = sm01 + BA;                // (s0m+B0, s1m+B2)
    v2f m0b = sm23 + mk2(BB.y, BB.x);   // (s2m+B3, s3m+B1)
    float m1 = max4(m1a.x, m1a.y, m1b.x, m1b.y);
    float m0 = max4(m0a.x, m0a.y, m0b.x, m0b.y);
    float llr = m1 - m0;
    // 2*p[k] == x[k] + y[k]
    float val = finalLLR ? llr : (llr - p - qq);
    dst[wi[k]] = val;
    a01 = mk2(fmaxf(sm01.x, sp01.y), fmaxf(sp23.x, sm23.y));  // (a0', a1')
    a23 = mk2(fmaxf(sp01.x, sm01.y), fmaxf(sm23.x, sp23.y));  // (a2', a3')
  }
}

__device__ __forceinline__ unsigned fsm_compose(unsigned f, unsigned g) {
  unsigned nm = 0;
#pragma unroll
  for (int s = 0; s < 4; ++s) {
    unsigned gs = (g >> (8 * s)) & 3u;
    nm |= ((f >> (8 * gs)) & 0xFFu) << (8 * s);
  }
  return nm;
}

__global__ __launch_bounds__(TPR, 2) void turbo_kernel(
    const int* __restrict__ xg, const float* __restrict__ n1g,
    const float* __restrict__ n2g, const float* __restrict__ n3g,
    const int* __restrict__ pg, float* __restrict__ outg) {
  __shared__ SM sm;
  const int tid = threadIdx.x;
  const int lane = tid & 63, w = tid >> 6;
  const int base = tid * SCH;
  const size_t rb = (size_t)blockIdx.x * KLEN;

  // ---- load inputs ----
  int* Ai = (int*)sm.A;
  for (int i = tid; i < KLEN; i += TPR) {
    sm.perm[i] = (unsigned short)pg[i];
    int xv = xg[rb + i];
    Ai[i] = xv;
    sm.y1[i] = (2.f * xv - 1.f) + n1g[rb + i];
    sm.Lint[i] = 0.f;
  }
  float q2[SCH], q3[SCH];
  {
    size_t g0 = rb + (size_t)base;
#pragma unroll
    for (int k = 0; k < SCH; ++k) { q2[k] = n2g[g0 + k]; q3[k] = n3g[g0 + k]; }
  }
  __syncthreads();

  // ---- one-time: invp, interleaved systematic ----
  for (int i = tid; i < KLEN; i += TPR) {
    sm.invp[sm.perm[i]] = (unsigned short)i;
    sm.y1i[i] = sm.y1[sm.perm[i]];
  }

  // ---- RSC encode via FSM hierarchical scan ----
  unsigned ub1 = 0, ub2 = 0;
#pragma unroll
  for (int k = 0; k < SCH; ++k) {
    int t = base + k;
    ub1 |= (unsigned)(Ai[t] & 1) << k;
    ub2 |= (unsigned)(Ai[sm.perm[t]] & 1) << k;
  }
  unsigned m1 = 0x03020100u, m2 = 0x03020100u;
#pragma unroll
  for (int k = 0; k < SCH; ++k) {
    unsigned st1 = ((ub1 >> k) & 1) ? 0x03010002u : 0x01030200u;
    unsigned st2 = ((ub2 >> k) & 1) ? 0x03010002u : 0x01030200u;
    m1 = fsm_compose(st1, m1);
    m2 = fsm_compose(st2, m2);
  }
#pragma unroll
  for (int i = 0; i < 6; ++i) {
    const int d = 1 << i;
    unsigned t1 = __shfl_up(m1, d), t2 = __shfl_up(m2, d);
    if (lane >= d) { m1 = fsm_compose(m1, t1); m2 = fsm_compose(m2, t2); }
  }
  if (lane == 63) { sm.eT[w][0] = m1; sm.eT[w][1] = m2; }
  __syncthreads();
  {
    unsigned W1 = 0x03020100u, W2 = 0x03020100u;
    if (w >= 1) { W1 = sm.eT[0][0]; W2 = sm.eT[0][1]; }
    if (w >= 2) { W1 = fsm_compose(sm.eT[1][0], W1); W2 = fsm_compose(sm.eT[1][1], W2); }
    if (w >= 3) { W1 = fsm_compose(sm.eT[2][0], W1); W2 = fsm_compose(sm.eT[2][1], W2); }
    unsigned f1 = fsm_compose(m1, W1), f2 = fsm_compose(m2, W2);
    unsigned pf1 = __shfl_up(f1, 1), pf2 = __shfl_up(f2, 1);
    int s1 = (tid == 0) ? 0 : (lane == 0 ? (int)(W1 & 3u) : (int)(pf1 & 3u));
    int s2 = (tid == 0) ? 0 : (lane == 0 ? (int)(W2 & 3u) : (int)(pf2 & 3u));
#pragma unroll
    for (int k = 0; k < SCH; ++k) {
      { int u = (ub1 >> k) & 1, a = u ^ (s1 >> 1) ^ (s1 & 1), par = a ^ (s1 & 1);
        q2[k] += 2.f * par - 1.f; s1 = (a << 1) | (s1 >> 1); }
      { int u = (ub2 >> k) & 1, a = u ^ (s2 >> 1) ^ (s2 & 1), par = a ^ (s2 & 1);
        q3[k] += 2.f * par - 1.f; s2 = (a << 1) | (s2 >> 1); }
    }
  }
  __syncthreads();  // bits consumed; A becomes interleaved-La buffer

  // ---- cache scatter indices in registers (constant across iterations) ----
  int wi1[SCH], wi2[SCH];
#pragma unroll
  for (int k = 0; k < SCH; ++k) {
    wi1[k] = (int)sm.invp[base + k];
    wi2[k] = (int)sm.perm[base + k];
  }

  // ---- 6 turbo iterations ----
#pragma unroll 1
  for (int it = 0; it < 6; ++it) {
    bcjr_pass(sm.y1, sm.Lint, sm.A, wi1, 0, q2, sm.fT, sm.rT, base, lane, w);
    __syncthreads();
    const int fin = (it == 5);
    bcjr_pass(sm.y1i, sm.A, sm.Lint, wi2, fin, q3, sm.fT, sm.rT, base, lane, w);
    __syncthreads();
  }

  // ---- Lint holds deinterleaved L2; coalesced store ----
  for (int i = tid; i < KLEN; i += TPR) outg[rb + i] = sm.Lint[i];
}

extern "C" void kernel_launch(void* const* d_in, const int* in_sizes, int n_in,
                              void* d_out, int out_size, void* d_ws, size_t ws_size,
                              hipStream_t stream) {
  (void)n_in; (void)d_ws; (void)ws_size; (void)out_size;
  const int* x    = (const int*)d_in[0];
  const float* n1 = (const float*)d_in[1];
  const float* n2 = (const float*)d_in[2];
  const float* n3 = (const float*)d_in[3];
  const int* perm = (const int*)d_in[4];
  float* out = (float*)d_out;
  const int K = in_sizes[4];       // 2048
  const int B = in_sizes[0] / K;   // 512 rows, one per block
  turbo_kernel<<<B, TPR, 0, stream>>>(x, n1, n2, n3, perm, out);
}